// Round 10
// baseline (406.535 us; speedup 1.0000x reference)
//
#include <hip/hip_runtime.h>

typedef unsigned short u16;
typedef __attribute__((ext_vector_type(8))) short short8;
typedef __attribute__((ext_vector_type(16))) float f32x16;
typedef __attribute__((ext_vector_type(4))) unsigned short us4;

__device__ __forceinline__ u16 f2bf(float f) {
    unsigned u = __float_as_uint(f);
    u += 0x7fffu + ((u >> 16) & 1u);   // round-to-nearest-even
    return (u16)(u >> 16);
}
__device__ __forceinline__ float bf2f(u16 h) {
    return __uint_as_float(((unsigned)h) << 16);
}

// ---------------- X f32 -> bf16 (4 elems/thread) ----------------
__global__ __launch_bounds__(256) void k_cvt(const float* __restrict__ in,
                                             u16* __restrict__ out, long n) {
    long i = ((long)blockIdx.x * 256 + threadIdx.x) * 4;
    if (i >= n) return;
    float4 v = *(const float4*)(in + i);
    us4 o;
    o.x = f2bf(v.x); o.y = f2bf(v.y); o.z = f2bf(v.z); o.w = f2bf(v.w);
    *(us4*)(out + i) = o;
}

// ---------------- W (K,N) f32 -> Wt (N,K) bf16, block-tri mask ----------------
__global__ __launch_bounds__(256) void k_transpose(const float* __restrict__ W,
                                                   u16* __restrict__ Wt,
                                                   int K, int N, int mask) {
    __shared__ float tile[32][33];
    const int n0 = blockIdx.x * 32, k0 = blockIdx.y * 32;
    const int tx = threadIdx.x, ty = threadIdx.y;
    if (mask && ((k0 >> 6) > (n0 >> 6))) {
        if (k0 >= ((n0 >> 8) + 1) * 256) return;   // never read by varK GEMM
#pragma unroll
        for (int j = 0; j < 32; j += 8)
            Wt[(size_t)(n0 + ty + j) * K + (k0 + tx)] = 0;
        return;
    }
#pragma unroll
    for (int j = 0; j < 32; j += 8)
        tile[ty + j][tx] = W[(size_t)(k0 + ty + j) * N + (n0 + tx)];
    __syncthreads();
#pragma unroll
    for (int j = 0; j < 32; j += 8)
        Wt[(size_t)(n0 + ty + j) * K + (k0 + tx)] = f2bf(tile[tx][ty + j]);
}

// ---------------- extract W3[:, N-1] ----------------
__global__ __launch_bounds__(256) void k_extract(const float* __restrict__ W3,
                                                 float* __restrict__ col, int N) {
    int k = blockIdx.x * 256 + threadIdx.x;
    col[k] = W3[(size_t)k * N + (N - 1)];
}

// ---------------- bf16 GEMM: C = relu(A @ Bt^T + bias) -> bf16 ----------------
// 256x256 tile, BK=32, 512 threads (8 waves 2x4), QUAD-buffered LDS (4x32 KiB),
// 2 phases/tile, stage T+3 during T.  R10: 32x32x16 MFMA (2382 TF ceiling vs
// 2075 for 16x16; half the MFMA instructions).  Per wave per K32-tile:
// 16 mfma_32x32x16 = (4 mf x 2 nf) x 2 ks, split 8+8 over two phases with
// X/Y register alternation (p0 consumes ks0 read last phase + reads ks1;
// p1 consumes ks1 + reads next tile ks0).  Schedule/sync identical to R9:
// tail-aware vmcnt(6/4/0) before the p0-end barrier; builtin barriers (no
// memory-clobber asm); compiler-counted lgkm waits; XOR-swizzle
// slot^=(row>>1)&3 both sides.  A/B frag: row=lane&31, k=(lane>>5)*8.
// C/D frag (m74/m101): col=lane&31, row=(reg&3)+8*(reg>>2)+4*(lane>>5).
#define BM 256
#define BN 256
#define BK 32
#define BUFE 16384                     // elems per buffer: A 8192 | B 8192
#define GLDS(src, dst)                                                          \
    __builtin_amdgcn_global_load_lds(                                           \
        (const __attribute__((address_space(1))) void*)(src),                   \
        (__attribute__((address_space(3))) void*)(dst), 16, 0, 0)

__global__ __launch_bounds__(512, 2) void k_gemm(const u16* __restrict__ A,
                                                 const u16* __restrict__ Bt,
                                                 const float* __restrict__ bias,
                                                 u16* __restrict__ C,
                                                 int M, int N, int K, int varK) {
    __shared__ __align__(16) u16 lds[4 * BUFE];   // 128 KiB

    const int d = blockIdx.y * gridDim.x + blockIdx.x;
    int bx, by;
    if (varK) {   // LPT: heavy column-tiles (large keff) first
        bx = (int)gridDim.x - 1 - (d / (int)gridDim.y);
        by = d % (int)gridDim.y;
    } else {      // bijective XCD swizzle (nwg divisible by 8)
        const int nwg = (int)(gridDim.x * gridDim.y);
        const int cpx = nwg >> 3;
        const int swz = (d & 7) * cpx + (d >> 3);
        bx = swz % (int)gridDim.x;
        by = swz / (int)gridDim.x;
    }

    const int tid = (int)threadIdx.x;
    const int lane = tid & 63, wv = tid >> 6;
    const int wm = wv >> 2, wn = wv & 3;          // wave tile: 128(m) x 64(n)
    const int keff = varK ? min(K, (bx + 1) * BN) : K;
    const int nt = keff >> 5;                     // K-tiles of 32; nt >= 8

    const u16* Ab = A + (size_t)by * BM * K;
    const u16* Bb = Bt + (size_t)bx * BN * K;

    // ---- staging: chunk = 128 rows x 32 k = 8KB = 1 gload/thread; 2+2/tile ----
    // dest linear: buf + [A0|B 8192] + ci*4096 + tid*8
    // source row = ci*128 + (tid>>2); k-slot = (tid&3) ^ ((row>>1)&3)  (pre-swizzle)
    const int tr = tid >> 2, ts = tid & 3;
    const int ss = ts ^ ((tr >> 1) & 3);
    const u16* aSrc = Ab + (size_t)tr * K + ss * 8;
    const u16* bSrc = Bb + (size_t)tr * K + ss * 8;

#define STA(tt, ci, dbuf) GLDS(aSrc + (size_t)(tt) * BK + (size_t)(ci) * 128 * K, \
                               lds + (dbuf) + (ci) * 4096 + tid * 8)
#define STB(tt, ci, dbuf) GLDS(bSrc + (size_t)(tt) * BK + (size_t)(ci) * 128 * K, \
                               lds + (dbuf) + 8192 + (ci) * 4096 + tid * 8)

    // ---- fragment reads: row = base + lane&31; slot = (l5 ^ sw2 ^ (ks<<1)) ----
    const int l31 = lane & 31, l5 = lane >> 5;
    const int sw2 = (l31 >> 1) & 3;               // row-derived XOR (mf*32 ≡ 0 mod 4)
    const int sbase = l5 ^ sw2;
    const int arow = wm * 128 + l31;
    const int brow = wn * 64 + l31;

#define RDA(dst, ks, dbuf)                                                           \
    {                                                                                \
        _Pragma("unroll")                                                            \
        for (int mf = 0; mf < 4; ++mf)                                               \
            dst[mf] = *(const short8*)(lds + (dbuf) + (arow + mf * 32) * 32          \
                                       + ((sbase ^ ((ks) << 1))) * 8);               \
    }
#define RDB(dst, ks, dbuf)                                                           \
    {                                                                                \
        _Pragma("unroll")                                                            \
        for (int nf = 0; nf < 2; ++nf)                                               \
            dst[nf] = *(const short8*)(lds + (dbuf) + 8192 + (brow + nf * 32) * 32   \
                                       + ((sbase ^ ((ks) << 1))) * 8);               \
    }
#define MFMA8(afS, bfS)                                                              \
    {                                                                                \
        __builtin_amdgcn_s_setprio(1);                                              \
        _Pragma("unroll")                                                            \
        for (int mf = 0; mf < 4; ++mf)                                               \
            _Pragma("unroll")                                                        \
            for (int nf = 0; nf < 2; ++nf)                                           \
                acc[mf][nf] = __builtin_amdgcn_mfma_f32_32x32x16_bf16(               \
                    afS[mf], bfS[nf], acc[mf][nf], 0, 0, 0);                         \
        __builtin_amdgcn_s_setprio(0);                                              \
    }
#define PHASE_END                                                 \
    __builtin_amdgcn_sched_barrier(0);                            \
    __builtin_amdgcn_s_barrier();                                 \
    __builtin_amdgcn_sched_barrier(0);
#define VMW(n)                                                    \
    __builtin_amdgcn_sched_barrier(0);                            \
    asm volatile("s_waitcnt vmcnt(" #n ")");                      \
    __builtin_amdgcn_sched_barrier(0);

    f32x16 acc[4][2];
#pragma unroll
    for (int i = 0; i < 4; ++i)
#pragma unroll
        for (int j = 0; j < 2; ++j)
#pragma unroll
            for (int r = 0; r < 16; ++r)
                acc[i][j][r] = 0.f;

    short8 afX[4], afY[4], bfX[2], bfY[2];

    // ---- prologue: stage tiles 0,1,2 (12 loads); force tile 0 (vmcnt(8))
    //      BEFORE the barrier (cross-wave propagation) ----
    STA(0, 0, 0);     STA(0, 1, 0);     STB(0, 0, 0);     STB(0, 1, 0);
    STA(1, 0, BUFE);  STA(1, 1, BUFE);  STB(1, 0, BUFE);  STB(1, 1, BUFE);
    STA(2, 0, 2*BUFE);STA(2, 1, 2*BUFE);STB(2, 0, 2*BUFE);STB(2, 1, 2*BUFE);
    VMW(8)
    __builtin_amdgcn_s_barrier();
    __builtin_amdgcn_sched_barrier(0);
    RDA(afX, 0, 0);
    RDB(bfX, 0, 0);

    // Ledger (per wave): tile U's chunks staged at (U-3).{p0:A, p1:B}.
    // At T.p0-end (after MFMA, before barrier): force tile T+1's A+B landed;
    // outstanding newer = {T+2.a (T-1.p0), T+2.b (T-1.p1), T+3.a (T.p0)}
    //   -> vmcnt 6 / 4 / 0 tail-aware; skipped when T+1>=nt.
    // WAR: STA(T+3) writes buf (T-1)&3; tile T-1's last reads (T-1.p0, ks1)
    // are drained by the compiler's counted lgkm wait before T-1.p1's MFMA,
    // which precedes the T-1.p1 barrier, which precedes T.p0's stages.
    for (int T = 0; T < nt; ++T) {
        const int bT = (T & 3) * BUFE;
        const int bY = ((T + 1) & 3) * BUFE;
        const int bZ = ((T + 3) & 3) * BUFE;
        // ---- p0: read T.ks1 -> Y; stage T+3.a; MFMA (X = T.ks0); vmcnt; bar ----
        RDA(afY, 1, bT);
        RDB(bfY, 1, bT);
        if (T + 3 < nt) { STA(T + 3, 0, bZ); STA(T + 3, 1, bZ); }
        MFMA8(afX, bfX);
        if (T + 1 < nt) {
            if (T + 3 < nt) { VMW(6) } else if (T + 2 < nt) { VMW(4) } else { VMW(0) }
        }
        PHASE_END;
        // ---- p1: read T+1.ks0 -> X; stage T+3.b; MFMA (Y = T.ks1); bar ----
        if (T + 1 < nt) {
            RDA(afX, 0, bY);
            RDB(bfX, 0, bY);
        }
        if (T + 3 < nt) { STB(T + 3, 0, bZ); STB(T + 3, 1, bZ); }
        MFMA8(afY, bfY);
        PHASE_END;
    }

    // ---- epilogue: bias + relu + bf16 store ----
    // C/D 32x32: col = lane&31, row = (reg&3) + 8*(reg>>2) + 4*(lane>>5)
    const int rbase = by * BM + wm * 128 + 4 * l5;
    const int cbase = bx * BN + wn * 64 + l31;
#pragma unroll
    for (int nf = 0; nf < 2; ++nf) {
        const int gc = cbase + nf * 32;
        const float bv = bias[gc];
#pragma unroll
        for (int mf = 0; mf < 4; ++mf) {
#pragma unroll
            for (int reg = 0; reg < 16; ++reg) {
                int gr = rbase + mf * 32 + (reg & 3) + 8 * (reg >> 2);
                float h = acc[mf][nf][reg] + bv;
                h = fmaxf(h, 0.0f);
                C[(size_t)gr * N + gc] = f2bf(h);
            }
        }
    }
#undef STA
#undef STB
#undef RDA
#undef RDB
#undef MFMA8
#undef PHASE_END
#undef VMW
}

// ---------------- final matvec: out[m] = act[m,:] . col + b3[K-1] ----------------
__global__ __launch_bounds__(256) void k_matvec(const u16* __restrict__ act,
                                                const float* __restrict__ col,
                                                const float* __restrict__ b3,
                                                float* __restrict__ out, int K) {
    const int m = blockIdx.x, t = (int)threadIdx.x;
    const u16* row = act + (size_t)m * K;
    float acc = 0.f;
#pragma unroll
    for (int j = 0; j < 2; ++j) {
        int base = t * 16 + j * 8;
        short8 v = *(const short8*)(row + base);
#pragma unroll
        for (int u = 0; u < 8; ++u)
            acc += bf2f((u16)v[u]) * col[base + u];
    }
#pragma unroll
    for (int off = 32; off > 0; off >>= 1)
        acc += __shfl_down(acc, off);
    __shared__ float red[4];
    if ((t & 63) == 0) red[t >> 6] = acc;
    __syncthreads();
    if (t == 0) out[m] = red[0] + red[1] + red[2] + red[3] + b3[K - 1];
}

extern "C" void kernel_launch(void* const* d_in, const int* in_sizes, int n_in,
                              void* d_out, int out_size, void* d_ws, size_t ws_size,
                              hipStream_t stream) {
    const float* X  = (const float*)d_in[0];
    const float* W0 = (const float*)d_in[1];
    const float* b0 = (const float*)d_in[2];
    const float* W1 = (const float*)d_in[3];
    const float* b1 = (const float*)d_in[4];
    const float* W2 = (const float*)d_in[5];
    const float* b2 = (const float*)d_in[6];
    const float* W3 = (const float*)d_in[7];
    const float* b3 = (const float*)d_in[8];
    float* out = (float*)d_out;

    const int M = 8192, K0 = 1024, H = 4096;

    char* ws = (char*)d_ws;
    u16* Wt    = (u16*)(ws);                               // 33.5 MB (reused)
    u16* actA  = (u16*)(ws + 33554432);                    // 67.1 MB
    u16* actB  = (u16*)(ws + 33554432 + 67108864);         // 67.1 MB
    u16* Xb    = actB;                                     // alias: dead before actB written
    float* col = (float*)(ws + 33554432 + 2 * 67108864);   // 16 KB

    // 1. X -> bf16
    k_cvt<<<dim3((M * K0) / 1024), 256, 0, stream>>>(X, Xb, (long)M * K0);
    // 2. W0^T (no mask)
    k_transpose<<<dim3(H / 32, K0 / 32), dim3(32, 8), 0, stream>>>(W0, Wt, K0, H, 0);
    // 3. h0 = relu(X @ W0 + b0)
    k_gemm<<<dim3(H / BN, M / BM), 512, 0, stream>>>(Xb, Wt, b0, actA, M, H, K0, 0);
    // 4. W1^T masked
    k_transpose<<<dim3(H / 32, H / 32), dim3(32, 8), 0, stream>>>(W1, Wt, H, H, 1);
    // 5. h1 = relu(h0 @ W1eff + b1)   (variable-K per column tile, LPT order)
    k_gemm<<<dim3(H / BN, M / BM), 512, 0, stream>>>(actA, Wt, b1, actB, M, H, H, 1);
    // 6. W2^T masked
    k_transpose<<<dim3(H / 32, H / 32), dim3(32, 8), 0, stream>>>(W2, Wt, H, H, 1);
    // 7. h2 = relu(h1 @ W2eff + b2)
    k_gemm<<<dim3(H / BN, M / BM), 512, 0, stream>>>(actB, Wt, b2, actA, M, H, H, 1);
    // 8. W3 column 4095
    k_extract<<<dim3(H / 256), 256, 0, stream>>>(W3, col, H);
    // 9. out = h2 @ w3col + b3[4095]
    k_matvec<<<dim3(M), 256, 0, stream>>>(actA, col, b3, out, H);
}

// Round 11
// 404.928 us; speedup vs baseline: 1.0040x; 1.0040x over previous
//
#include <hip/hip_runtime.h>

typedef unsigned short u16;
typedef __attribute__((ext_vector_type(8))) short short8;
typedef __attribute__((ext_vector_type(4))) float f32x4;
typedef __attribute__((ext_vector_type(4))) unsigned short us4;

__device__ __forceinline__ u16 f2bf(float f) {
    unsigned u = __float_as_uint(f);
    u += 0x7fffu + ((u >> 16) & 1u);   // round-to-nearest-even
    return (u16)(u >> 16);
}
__device__ __forceinline__ float bf2f(u16 h) {
    return __uint_as_float(((unsigned)h) << 16);
}

// ---------------- X f32 -> bf16 (4 elems/thread) ----------------
__global__ __launch_bounds__(256) void k_cvt(const float* __restrict__ in,
                                             u16* __restrict__ out, long n) {
    long i = ((long)blockIdx.x * 256 + threadIdx.x) * 4;
    if (i >= n) return;
    float4 v = *(const float4*)(in + i);
    us4 o;
    o.x = f2bf(v.x); o.y = f2bf(v.y); o.z = f2bf(v.z); o.w = f2bf(v.w);
    *(us4*)(out + i) = o;
}

// ---------------- W (K,N) f32 -> Wt (N,K) bf16, block-tri mask ----------------
__global__ __launch_bounds__(256) void k_transpose(const float* __restrict__ W,
                                                   u16* __restrict__ Wt,
                                                   int K, int N, int mask) {
    __shared__ float tile[32][33];
    const int n0 = blockIdx.x * 32, k0 = blockIdx.y * 32;
    const int tx = threadIdx.x, ty = threadIdx.y;
    if (mask && ((k0 >> 6) > (n0 >> 6))) {
        if (k0 >= ((n0 >> 8) + 1) * 256) return;   // never read by varK GEMM
#pragma unroll
        for (int j = 0; j < 32; j += 8)
            Wt[(size_t)(n0 + ty + j) * K + (k0 + tx)] = 0;
        return;
    }
#pragma unroll
    for (int j = 0; j < 32; j += 8)
        tile[ty + j][tx] = W[(size_t)(k0 + ty + j) * N + (n0 + tx)];
    __syncthreads();
#pragma unroll
    for (int j = 0; j < 32; j += 8)
        Wt[(size_t)(n0 + ty + j) * K + (k0 + tx)] = f2bf(tile[tx][ty + j]);
}

// ---------------- extract W3[:, N-1] ----------------
__global__ __launch_bounds__(256) void k_extract(const float* __restrict__ W3,
                                                 float* __restrict__ col, int N) {
    int k = blockIdx.x * 256 + threadIdx.x;
    col[k] = W3[(size_t)k * N + (N - 1)];
}

// ---------------- bf16 GEMM: C = relu(A @ Bt^T + bias) -> bf16 ----------------
// m201-template reconstruction: 256x256 tile, BK=64, 512 threads (8 waves 2x4),
// 2 LDS buffers x (A 2-khalf + B 2-khalf) = 128 KiB.  4 phases per K64-tile;
// each phase = [ds_read 8 or 4 b128 (THIS phase's operands) | stage 1 granule
// (2 GLDS) | BAR | lgkmcnt(0)+SB | setprio1 | 16 MFMA | setprio0 | BAR].
// vmcnt(6) once per tile at ph3 (2 loads x 3 granules in flight) — before the
// barrier so landing propagates cross-wave.  Granule schedule (all targets
// dead >=1 barrier before overwrite): ph0: Akh1(T+1); ph1: Bkh0(T+2);
// ph2: Akh0(T+2); ph3: Bkh1(T+2).  R9's 0-conflict XOR swizzle per khalf.
#define BM 256
#define BN 256
#define BK 64
#define BUFE 32768                     // elems per buffer: A 16384 | B 16384
#define GLDS(src, dst)                                                          \
    __builtin_amdgcn_global_load_lds(                                           \
        (const __attribute__((address_space(1))) void*)(src),                   \
        (__attribute__((address_space(3))) void*)(dst), 16, 0, 0)

__global__ __launch_bounds__(512, 2) void k_gemm(const u16* __restrict__ A,
                                                 const u16* __restrict__ Bt,
                                                 const float* __restrict__ bias,
                                                 u16* __restrict__ C,
                                                 int M, int N, int K, int varK) {
    __shared__ __align__(16) u16 lds[2 * BUFE];   // 128 KiB

    const int d = blockIdx.y * gridDim.x + blockIdx.x;
    int bx, by;
    if (varK) {   // LPT: heavy column-tiles (large keff) first
        bx = (int)gridDim.x - 1 - (d / (int)gridDim.y);
        by = d % (int)gridDim.y;
    } else {      // bijective XCD swizzle (nwg divisible by 8)
        const int nwg = (int)(gridDim.x * gridDim.y);
        const int cpx = nwg >> 3;
        const int swz = (d & 7) * cpx + (d >> 3);
        bx = swz % (int)gridDim.x;
        by = swz / (int)gridDim.x;
    }

    const int tid = (int)threadIdx.x;
    const int lane = tid & 63, wv = tid >> 6;
    const int wm = wv >> 2, wn = wv & 3;          // wave tile: 128(m) x 64(n)
    const int keff = varK ? min(K, (bx + 1) * BN) : K;
    const int nt = keff >> 6;                     // K-tiles of 64; nt multiple of 4

    const u16* Ab = A + (size_t)by * BM * K;
    const u16* Bb = Bt + (size_t)bx * BN * K;

    // ---- staging: granule = 16 KB = one khalf of A or B = 2 GLDS/thread ----
    // LDS: buf(b)=b*BUFE; A at +0, B at +16384; khalf kh at +kh*8192.
    // granule layout: idx = tid + j*512 (j=0,1); row = idx>>2; slot = idx&3;
    // dest elem = idx*8 (linear); source k = tile*64 + kh*32 + (slot^((row>>1)&3))*8.
    const int srow = tid >> 2, sslot = tid & 3;
    const int ss = sslot ^ ((srow >> 1) & 3);     // same for j=1 (row+128: +64 even)
    const u16* aSrc0 = Ab + (size_t)srow * K + ss * 8;
    const u16* aSrc1 = Ab + (size_t)(srow + 128) * K + ss * 8;
    const u16* bSrc0 = Bb + (size_t)srow * K + ss * 8;
    const u16* bSrc1 = Bb + (size_t)(srow + 128) * K + ss * 8;

#define STGA(tt, kh)                                                            \
    {                                                                           \
        const int db = (((tt) & 1) * BUFE) + (kh) * 8192;                       \
        const size_t so = (size_t)(tt) * 64 + (kh) * 32;                        \
        GLDS(aSrc0 + so, lds + db + tid * 8);                                   \
        GLDS(aSrc1 + so, lds + db + 4096 + tid * 8);                            \
    }
#define STGB(tt, kh)                                                            \
    {                                                                           \
        const int db = (((tt) & 1) * BUFE) + 16384 + (kh) * 8192;               \
        const size_t so = (size_t)(tt) * 64 + (kh) * 32;                        \
        GLDS(bSrc0 + so, lds + db + tid * 8);                                   \
        GLDS(bSrc1 + so, lds + db + 4096 + tid * 8);                            \
    }

    // ---- fragment reads (R9 layout per khalf: row stride 32 elems, swizzled
    //      slot = (lane>>4) ^ ((l15>>1)&3); 0 bank conflicts measured) ----
    const int l15 = lane & 15;
    const int sw = (lane >> 4) ^ ((l15 >> 1) & 3);
    const int arow = wm * 128 + l15;
    const int brow = wn * 64 + l15;

#define RDA(mh, ks, bT)                                                         \
    {                                                                           \
        _Pragma("unroll")                                                       \
        for (int i = 0; i < 4; ++i)                                             \
            af[i] = *(const short8*)(lds + (bT) + (ks) * 8192 +                  \
                                     (arow + (mh) * 64 + i * 16) * 32 + sw * 8);\
    }
#define RDB(ks, bT)                                                             \
    {                                                                           \
        _Pragma("unroll")                                                       \
        for (int nf = 0; nf < 4; ++nf)                                          \
            bf[nf] = *(const short8*)(lds + (bT) + 16384 + (ks) * 8192 +        \
                                      (brow + nf * 16) * 32 + sw * 8);          \
    }
#define MFMAQ(mh)                                                               \
    {                                                                           \
        __builtin_amdgcn_s_setprio(1);                                          \
        _Pragma("unroll")                                                       \
        for (int i = 0; i < 4; ++i)                                             \
            _Pragma("unroll")                                                   \
            for (int nf = 0; nf < 4; ++nf)                                      \
                acc[(mh) * 4 + i][nf] = __builtin_amdgcn_mfma_f32_16x16x32_bf16(\
                    af[i], bf[nf], acc[(mh) * 4 + i][nf], 0, 0, 0);             \
        __builtin_amdgcn_s_setprio(0);                                          \
    }
#define SB __builtin_amdgcn_sched_barrier(0)
#define BAR __builtin_amdgcn_s_barrier()
#define LGKM0 { SB; asm volatile("s_waitcnt lgkmcnt(0)"); SB; }

    f32x4 acc[8][4];
#pragma unroll
    for (int i = 0; i < 8; ++i)
#pragma unroll
        for (int j = 0; j < 4; ++j)
            acc[i][j] = (f32x4){0.f, 0.f, 0.f, 0.f};

    short8 af[4], bf[4];

    // ---- prologue: tile0 fully + tile1 {Akh0,Bkh0,Bkh1} (Akh1(1) comes at
    //      ph0 of tile0).  vmcnt(6) forces tile0 (allows tile1's 3 granules). ----
    STGA(0, 0); STGA(0, 1); STGB(0, 0); STGB(0, 1);
    STGA(1, 0); STGB(1, 0); STGB(1, 1);
    SB; asm volatile("s_waitcnt vmcnt(6)"); SB;
    BAR; SB;

    for (int T = 0; T < nt; ++T) {
        const int bT = (T & 1) * BUFE;
        // ---- ph0: read A(mh0,ks0)+B(ks0); stage Akh1(T+1); BAR; lgkm0; MFMA ----
        RDA(0, 0, bT);
        RDB(0, bT);
        if (T + 1 < nt) STGA(T + 1, 1);
        SB; BAR;
        LGKM0;
        MFMAQ(0);
        SB; BAR;
        // ---- ph1: read A(mh1,ks0); stage Bkh0(T+2); BAR; lgkm0; MFMA ----
        RDA(1, 0, bT);
        if (T + 2 < nt) STGB(T + 2, 0);
        SB; BAR;
        LGKM0;
        MFMAQ(1);
        SB; BAR;
        // ---- ph2: read A(mh0,ks1)+B(ks1); stage Akh0(T+2); BAR; lgkm0; MFMA ----
        RDA(0, 1, bT);
        RDB(1, bT);
        if (T + 2 < nt) STGA(T + 2, 0);
        SB; BAR;
        LGKM0;
        MFMAQ(0);
        SB; BAR;
        // ---- ph3: read A(mh1,ks1); stage Bkh1(T+2); vmcnt; BAR; lgkm0; MFMA ----
        RDA(1, 1, bT);
        if (T + 2 < nt) STGB(T + 2, 1);
        if (T + 1 < nt) {
            if (T + 2 < nt) { SB; asm volatile("s_waitcnt vmcnt(6)"); SB; }
            else            { SB; asm volatile("s_waitcnt vmcnt(0)"); SB; }
        }
        SB; BAR;
        LGKM0;
        MFMAQ(1);
        SB; BAR;
    }

    // ---- epilogue: bias + relu + bf16 store (16x16 C/D layout, verified) ----
    const int rbase = by * BM + wm * 128 + (lane >> 4) * 4;
    const int cbase = bx * BN + wn * 64 + l15;
#pragma unroll
    for (int nf = 0; nf < 4; ++nf) {
        const int gc = cbase + nf * 16;
        const float bv = bias[gc];
#pragma unroll
        for (int mf = 0; mf < 8; ++mf) {
#pragma unroll
            for (int r = 0; r < 4; ++r) {
                int gr = rbase + mf * 16 + r;
                float h = acc[mf][nf][r] + bv;
                h = fmaxf(h, 0.0f);
                C[(size_t)gr * N + gc] = f2bf(h);
            }
        }
    }
#undef STGA
#undef STGB
#undef RDA
#undef RDB
#undef MFMAQ
#undef SB
#undef BAR
#undef LGKM0
}

// ---------------- final matvec: out[m] = act[m,:] . col + b3[K-1] ----------------
__global__ __launch_bounds__(256) void k_matvec(const u16* __restrict__ act,
                                                const float* __restrict__ col,
                                                const float* __restrict__ b3,
                                                float* __restrict__ out, int K) {
    const int m = blockIdx.x, t = (int)threadIdx.x;
    const u16* row = act + (size_t)m * K;
    float acc = 0.f;
#pragma unroll
    for (int j = 0; j < 2; ++j) {
        int base = t * 16 + j * 8;
        short8 v = *(const short8*)(row + base);
#pragma unroll
        for (int u = 0; u < 8; ++u)
            acc += bf2f((u16)v[u]) * col[base + u];
    }
#pragma unroll
    for (int off = 32; off > 0; off >>= 1)
        acc += __shfl_down(acc, off);
    __shared__ float red[4];
    if ((t & 63) == 0) red[t >> 6] = acc;
    __syncthreads();
    if (t == 0) out[m] = red[0] + red[1] + red[2] + red[3] + b3[K - 1];
}

extern "C" void kernel_launch(void* const* d_in, const int* in_sizes, int n_in,
                              void* d_out, int out_size, void* d_ws, size_t ws_size,
                              hipStream_t stream) {
    const float* X  = (const float*)d_in[0];
    const float* W0 = (const float*)d_in[1];
    const float* b0 = (const float*)d_in[2];
    const float* W1 = (const float*)d_in[3];
    const float* b1 = (const float*)d_in[4];
    const float* W2 = (const float*)d_in[5];
    const float* b2 = (const float*)d_in[6];
    const float* W3 = (const float*)d_in[7];
    const float* b3 = (const float*)d_in[8];
    float* out = (float*)d_out;

    const int M = 8192, K0 = 1024, H = 4096;

    char* ws = (char*)d_ws;
    u16* Wt    = (u16*)(ws);                               // 33.5 MB (reused)
    u16* actA  = (u16*)(ws + 33554432);                    // 67.1 MB
    u16* actB  = (u16*)(ws + 33554432 + 67108864);         // 67.1 MB
    u16* Xb    = actB;                                     // alias: dead before actB written
    float* col = (float*)(ws + 33554432 + 2 * 67108864);   // 16 KB

    // 1. X -> bf16
    k_cvt<<<dim3((M * K0) / 1024), 256, 0, stream>>>(X, Xb, (long)M * K0);
    // 2. W0^T (no mask)
    k_transpose<<<dim3(H / 32, K0 / 32), dim3(32, 8), 0, stream>>>(W0, Wt, K0, H, 0);
    // 3. h0 = relu(X @ W0 + b0)
    k_gemm<<<dim3(H / BN, M / BM), 512, 0, stream>>>(Xb, Wt, b0, actA, M, H, K0, 0);
    // 4. W1^T masked
    k_transpose<<<dim3(H / 32, H / 32), dim3(32, 8), 0, stream>>>(W1, Wt, H, H, 1);
    // 5. h1 = relu(h0 @ W1eff + b1)   (variable-K per column tile, LPT order)
    k_gemm<<<dim3(H / BN, M / BM), 512, 0, stream>>>(actA, Wt, b1, actB, M, H, H, 1);
    // 6. W2^T masked
    k_transpose<<<dim3(H / 32, H / 32), dim3(32, 8), 0, stream>>>(W2, Wt, H, H, 1);
    // 7. h2 = relu(h1 @ W2eff + b2)
    k_gemm<<<dim3(H / BN, M / BM), 512, 0, stream>>>(actB, Wt, b2, actA, M, H, H, 1);
    // 8. W3 column 4095
    k_extract<<<dim3(H / 256), 256, 0, stream>>>(W3, col, H);
    // 9. out = h2 @ w3col + b3[4095]
    k_matvec<<<dim3(M), 256, 0, stream>>>(actA, col, b3, out, H);
}